// Round 13
// baseline (58.064 us; speedup 1.0000x reference)
//
#include <hip/hip_runtime.h>
#include <hip/hip_bf16.h>
#include <math.h>

typedef __attribute__((ext_vector_type(8))) short bf16x8;
typedef __attribute__((ext_vector_type(4))) float f32x4;
typedef unsigned short ushort_t;

#define NP 14400     // real patches per video
#define NPK 14592    // padded rows/cols (114×128 rows; 228 groups of 64 cols)
#define NS 4         // column segments (3648 cols = 57 groups each)
#define NIT 57       // 64-col groups per segment
#define GRPB 12288   // bytes per 64-col group (64 cols * 96 k * 2B)

__device__ __forceinline__ ushort_t f2bf(float f) {
  unsigned u = __float_as_uint(f);
  u += 0x7FFF + ((u >> 16) & 1);   // RNE
  return (ushort_t)(u >> 16);
}
__device__ __forceinline__ float bf2f(ushort_t b) {
  return __uint_as_float(((unsigned)b) << 16);
}

// Fragment-order layouts (16B chunks laid out so consumer reads are
// base + lane*16 + imm — fully coalesced, conflict-free):
// K: chunk = ((p>>6)*12 + ((p>>4)&3)*3 + (d>>5))*64 + ((d>>3)&3)*16 + (p&15)
// Q: chunk = ((p>>4)*3 + (d>>5))*64 + ((d>>3)&3)*16 + (p&15)
__device__ __forceinline__ size_t kidx(int p, int d) {
  return ((size_t)(((p >> 6) * 12 + ((p >> 4) & 3) * 3 + (d >> 5)) * 64
          + ((d >> 3) & 3) * 16 + (p & 15))) * 8 + (d & 7);
}
__device__ __forceinline__ size_t qidx(int p, int d) {
  return ((size_t)(((p >> 4) * 3 + (d >> 5)) * 64
          + ((d >> 3) & 3) * 16 + (p & 15))) * 8 + (d & 7);
}

// ---------------- prep: patches -> bf16 in fragment order -----------------
// Q: slots 0..74 = bf16(-2*q), 75,76 = 1.0, rest 0; qn = fp32 norm.
// K: slots 0..74 = bf16(k), 75 = bf16(kn), 76 = bf16(kn residual), rest 0.
// Pad rows/cols (p >= NP): Q pad = zeros (qn=0); K pad = zero data with
// norm slot 3.39e38 (never wins the min).
__global__ __launch_bounds__(256) void prep_kernel(
    const float* __restrict__ resv, const float* __restrict__ valv,
    ushort_t* __restrict__ Qb, ushort_t* __restrict__ Kb,
    float* __restrict__ qn, unsigned* __restrict__ rminb) {
  int w = threadIdx.x >> 6;
  int lane = threadIdx.x & 63;
  int pg = blockIdx.x * 4 + w;          // 0..29183
  int isK = pg >= NPK;
  int p = isK ? pg - NPK : pg;          // 0..14591

  if (p >= NP) {                        // pad row/col
    if (isK) {
      Kb[kidx(p, lane)] = 0;
      if (lane < 32)
        Kb[kidx(p, lane + 64)] = (lane == 11) ? (ushort_t)0x7F7F : (ushort_t)0;
    } else {
      Qb[qidx(p, lane)] = 0;
      if (lane < 32) Qb[qidx(p, lane + 64)] = 0;
      if (lane == 0) { qn[p] = 0.f; rminb[p] = 0xFFFFFFFFu; }
    }
    return;
  }

  const float* src = isK ? valv : resv;
  int t = p / 3600; int rem = p - t * 3600;
  int y = rem / 60;  int x = rem - y * 60;

  float v0, v1 = 0.f;
  {
    int d = lane;  // < 75 always
    int c = d / 25; int r = d - c * 25; int dy = r / 5; int dx = r - dy * 5;
    v0 = src[((c * 4 + t) * 64 + (y + dy)) * 64 + (x + dx)];
  }
  if (lane < 11) {
    int d = lane + 64;
    int c = d / 25; int r = d - c * 25; int dy = r / 5; int dx = r - dy * 5;
    v1 = src[((c * 4 + t) * 64 + (y + dy)) * 64 + (x + dx)];
  }
  ushort_t b0 = f2bf(v0), b1 = f2bf(v1);
  float f0 = bf2f(b0), f1 = bf2f(b1);

  float sq = f0 * f0 + f1 * f1;
  #pragma unroll
  for (int off = 1; off < 64; off <<= 1) sq += __shfl_xor(sq, off, 64);

  if (isK) {
    ushort_t khi = f2bf(sq);
    ushort_t klo = f2bf(sq - bf2f(khi));
    ushort_t s1 = (lane < 11) ? b1
                : (lane == 11 ? khi : (lane == 12 ? klo : (ushort_t)0));
    Kb[kidx(p, lane)] = b0;
    if (lane < 32) Kb[kidx(p, lane + 64)] = s1;
  } else {
    ushort_t s0 = f2bf(-2.f * f0);
    ushort_t s1 = (lane < 11) ? f2bf(-2.f * f1)
                : ((lane == 11 || lane == 12) ? (ushort_t)0x3F80 : (ushort_t)0);
    Qb[qidx(p, lane)] = s0;
    if (lane < 32) Qb[qidx(p, lane + 64)] = s1;
    if (lane == 0) { qn[p] = sq; rminb[p] = 0xFFFFFFFFu; }
  }
}

// ------- main: wave tile 64 rows x 32 cols; block 128x64; depth-2 ---------
// 456 blocks = 8 x 57: ns = b&7 -> each XCD owns <=2 key segments (L2-hot).
// 24 MFMA per iter amortizes the fixed per-iter overhead 2x vs 12-MFMA iters.
__global__ __launch_bounds__(256, 2) void knn_kernel(
    const ushort_t* __restrict__ Qb, const ushort_t* __restrict__ Kb,
    unsigned* __restrict__ rminb) {
  int b = blockIdx.x;
  int lin = (b & 7) * 57 + (b >> 3);    // bijective: 456 = 8*57
  int ns = lin / 114, rowblk = lin - ns * 114;
  int brow = rowblk * 128;
  int lane = threadIdx.x & 63;
  int w = threadIdx.x >> 6;
  int wr = w >> 1, wc = w & 1;          // 2 row-waves x 2 col-waves
  int l15 = lane & 15, l4 = lane >> 4;

  // B: per iter the block consumes one 64-col group (GRPB bytes); wave (.,wc)
  // reads subgroups wc*2 + cf (cf=0,1), each 3 contiguous 1KB k-chunks.
  const char* gW = (const char*)Kb + (size_t)(ns * NIT) * GRPB
                   + wc * 2 * 3072 + lane * 16;

  // A: 64 rows x 96 k per wave, fragment-order, lane-contiguous.
  const char* Aw = (const char*)Qb + (size_t)((brow + wr * 64) >> 4) * 3072
                   + lane * 16;
  bf16x8 af[4][3];
  #pragma unroll
  for (int rt = 0; rt < 4; ++rt)
    #pragma unroll
    for (int ks = 0; ks < 3; ++ks)
      af[rt][ks] = *(const bf16x8*)(Aw + (rt * 3 + ks) * 1024);

  float rmin[4][4];
  #pragma unroll
  for (int rt = 0; rt < 4; ++rt)
    #pragma unroll
    for (int j = 0; j < 4; ++j) rmin[rt][j] = INFINITY;

  const f32x4 fz = {0.f, 0.f, 0.f, 0.f};

  // depth-2 register rotation; [buf][cf][ks], all indices literal
  bf16x8 bbuf[2][2][3];

  auto loadB = [&](int bi, int it) {
    const char* g = gW + (size_t)it * GRPB;
    #pragma unroll
    for (int cf = 0; cf < 2; ++cf)
      #pragma unroll
      for (int ks = 0; ks < 3; ++ks)
        bbuf[bi][cf][ks] = *(const bf16x8*)(g + cf * 3072 + ks * 1024);
  };

  auto compute = [&](int bi) {
    f32x4 acc[4][2];
    #pragma unroll
    for (int cf = 0; cf < 2; ++cf)
      #pragma unroll
      for (int rt = 0; rt < 4; ++rt)
        acc[rt][cf] = __builtin_amdgcn_mfma_f32_16x16x32_bf16(
            af[rt][0], bbuf[bi][cf][0], fz, 0, 0, 0);
    #pragma unroll
    for (int ks = 1; ks < 3; ++ks)
      #pragma unroll
      for (int cf = 0; cf < 2; ++cf)
        #pragma unroll
        for (int rt = 0; rt < 4; ++rt)
          acc[rt][cf] = __builtin_amdgcn_mfma_f32_16x16x32_bf16(
              af[rt][ks], bbuf[bi][cf][ks], acc[rt][cf], 0, 0, 0);
    #pragma unroll
    for (int rt = 0; rt < 4; ++rt)
      #pragma unroll
      for (int j = 0; j < 4; ++j)
        rmin[rt][j] = fminf(rmin[rt][j],
                            fminf(acc[rt][0][j], acc[rt][1][j]));  // v_min3
  };

  loadB(0, 0);
  loadB(1, 1);

  // depth-2, 57 iters: 27 doubles (0..53) + 3-iter tail
  int k = 0;
  #pragma unroll 1
  for (int tri = 0; tri < 27; ++tri, k += 2) {
    compute(0); loadB(0, k + 2);
    compute(1); loadB(1, k + 3);
  }
  // k == 54; in flight: (0,54),(1,55)
  compute(0); loadB(0, 56);   // iter 54
  compute(1);                  // iter 55
  compute(0);                  // iter 56

  // min over the 16 key-cols per l15 group, then device atomicMin per row
  #pragma unroll
  for (int rt = 0; rt < 4; ++rt)
    #pragma unroll
    for (int j = 0; j < 4; ++j) {
      float m = rmin[rt][j];
      m = fminf(m, __shfl_xor(m, 1, 64));
      m = fminf(m, __shfl_xor(m, 2, 64));
      m = fminf(m, __shfl_xor(m, 4, 64));
      m = fminf(m, __shfl_xor(m, 8, 64));
      if (l15 == 0) {
        unsigned bu = __float_as_uint(m);
        unsigned tu = bu ^ (unsigned)(((int)bu >> 31) | (int)0x80000000);
        atomicMin(&rminb[brow + wr * 64 + rt * 16 + l4 * 4 + j], tu);
      }
    }
}

// ------ final: decode + add qn + deterministic sum (one block) ------------
__global__ __launch_bounds__(1024) void final_kernel(
    const unsigned* __restrict__ rminb, const float* __restrict__ qn,
    float* __restrict__ out) {
  int t = threadIdx.x;
  float s = 0.f;
  for (int i = t; i < NP; i += 1024) {
    unsigned u = rminb[i];
    unsigned bu = (u & 0x80000000u) ? (u ^ 0x80000000u) : ~u;
    s += __uint_as_float(bu) + qn[i];
  }
  #pragma unroll
  for (int off = 32; off; off >>= 1) s += __shfl_down(s, off, 64);
  __shared__ float red[16];
  if ((t & 63) == 0) red[t >> 6] = s;
  __syncthreads();
  if (t == 0) {
    float tot = 0.f;
    #pragma unroll
    for (int i2 = 0; i2 < 16; ++i2) tot += red[i2];
    out[0] = tot;
  }
}

extern "C" void kernel_launch(void* const* d_in, const int* in_sizes, int n_in,
                              void* d_out, int out_size, void* d_ws, size_t ws_size,
                              hipStream_t stream) {
  const float* resv = (const float*)d_in[0];
  const float* valv = (const float*)d_in[1];
  char* ws = (char*)d_ws;
  ushort_t* Qb      = (ushort_t*)ws;                 // 2,801,664 B (14592 rows)
  ushort_t* Kb      = (ushort_t*)(ws + 2801664);     // 2,801,664 B (14592 cols)
  float* qn         = (float*)(ws + 5603328);        //    58,368 B
  unsigned* rminb   = (unsigned*)(ws + 5661696);     //    58,368 B
  float* out = (float*)d_out;

  prep_kernel<<<7296, 256, 0, stream>>>(resv, valv, Qb, Kb, qn, rminb);
  knn_kernel<<<456, 256, 0, stream>>>(Qb, Kb, rminb);
  final_kernel<<<1, 1024, 0, stream>>>(rminb, qn, out);
}

// Round 14
// 56.315 us; speedup vs baseline: 1.0311x; 1.0311x over previous
//
#include <hip/hip_runtime.h>
#include <hip/hip_bf16.h>
#include <math.h>

typedef __attribute__((ext_vector_type(8))) short bf16x8;
typedef __attribute__((ext_vector_type(4))) float f32x4;
typedef unsigned short ushort_t;

#define NP 14400     // real patches per video
#define NPK 14592    // padded rows/cols (228 groups of 64)
#define NS 4         // column segments (3648 cols = 57 groups each)
#define NIT 57       // 64-col tiles per segment
#define TILEB 12288  // bytes per 64-col tile (64 cols * 96 k * 2B)

__device__ __forceinline__ ushort_t f2bf(float f) {
  unsigned u = __float_as_uint(f);
  u += 0x7FFF + ((u >> 16) & 1);   // RNE
  return (ushort_t)(u >> 16);
}
__device__ __forceinline__ float bf2f(ushort_t b) {
  return __uint_as_float(((unsigned)b) << 16);
}

// Fragment-order layouts (16B chunks laid out so consumer reads are
// base + lane*16 + imm — fully coalesced, conflict-free):
// K: chunk = ((p>>6)*12 + ((p>>4)&3)*3 + (d>>5))*64 + ((d>>3)&3)*16 + (p&15)
// Q: chunk = ((p>>4)*3 + (d>>5))*64 + ((d>>3)&3)*16 + (p&15)
__device__ __forceinline__ size_t kidx(int p, int d) {
  return ((size_t)(((p >> 6) * 12 + ((p >> 4) & 3) * 3 + (d >> 5)) * 64
          + ((d >> 3) & 3) * 16 + (p & 15))) * 8 + (d & 7);
}
__device__ __forceinline__ size_t qidx(int p, int d) {
  return ((size_t)(((p >> 4) * 3 + (d >> 5)) * 64
          + ((d >> 3) & 3) * 16 + (p & 15))) * 8 + (d & 7);
}

// ---------------- prep: patches -> bf16 in fragment order -----------------
// Q: slots 0..74 = bf16(-2*q), 75,76 = 1.0, rest 0; qn = fp32 norm.
// K: slots 0..74 = bf16(k), 75 = bf16(kn), 76 = bf16(kn residual), rest 0.
// Pad rows/cols (p >= NP): Q pad = zeros (qn=0); K pad = zero data with
// norm slot 3.39e38 (never wins the min).
__global__ __launch_bounds__(256) void prep_kernel(
    const float* __restrict__ resv, const float* __restrict__ valv,
    ushort_t* __restrict__ Qb, ushort_t* __restrict__ Kb,
    float* __restrict__ qn, unsigned* __restrict__ rminb) {
  int w = threadIdx.x >> 6;
  int lane = threadIdx.x & 63;
  int pg = blockIdx.x * 4 + w;          // 0..29183
  int isK = pg >= NPK;
  int p = isK ? pg - NPK : pg;          // 0..14591

  if (p >= NP) {                        // pad row/col
    if (isK) {
      Kb[kidx(p, lane)] = 0;
      if (lane < 32)
        Kb[kidx(p, lane + 64)] = (lane == 11) ? (ushort_t)0x7F7F : (ushort_t)0;
    } else {
      Qb[qidx(p, lane)] = 0;
      if (lane < 32) Qb[qidx(p, lane + 64)] = 0;
      if (lane == 0) { qn[p] = 0.f; rminb[p] = 0xFFFFFFFFu; }
    }
    return;
  }

  const float* src = isK ? valv : resv;
  int t = p / 3600; int rem = p - t * 3600;
  int y = rem / 60;  int x = rem - y * 60;

  float v0, v1 = 0.f;
  {
    int d = lane;  // < 75 always
    int c = d / 25; int r = d - c * 25; int dy = r / 5; int dx = r - dy * 5;
    v0 = src[((c * 4 + t) * 64 + (y + dy)) * 64 + (x + dx)];
  }
  if (lane < 11) {
    int d = lane + 64;
    int c = d / 25; int r = d - c * 25; int dy = r / 5; int dx = r - dy * 5;
    v1 = src[((c * 4 + t) * 64 + (y + dy)) * 64 + (x + dx)];
  }
  ushort_t b0 = f2bf(v0), b1 = f2bf(v1);
  float f0 = bf2f(b0), f1 = bf2f(b1);

  float sq = f0 * f0 + f1 * f1;
  #pragma unroll
  for (int off = 1; off < 64; off <<= 1) sq += __shfl_xor(sq, off, 64);

  if (isK) {
    ushort_t khi = f2bf(sq);
    ushort_t klo = f2bf(sq - bf2f(khi));
    ushort_t s1 = (lane < 11) ? b1
                : (lane == 11 ? khi : (lane == 12 ? klo : (ushort_t)0));
    Kb[kidx(p, lane)] = b0;
    if (lane < 32) Kb[kidx(p, lane + 64)] = s1;
  } else {
    ushort_t s0 = f2bf(-2.f * f0);
    ushort_t s1 = (lane < 11) ? f2bf(-2.f * f1)
                : ((lane == 11 || lane == 12) ? (ushort_t)0x3F80 : (ushort_t)0);
    Qb[qidx(p, lane)] = s0;
    if (lane < 32) Qb[qidx(p, lane + 64)] = s1;
    if (lane == 0) { qn[p] = sq; rminb[p] = 0xFFFFFFFFu; }
  }
}

// ------- main: wave-private 64x16 tiles; acc double-buffer pipeline -------
// 912 blocks = 8 x 114 (bijective): each XCD owns ONE 0.7MB key segment.
// accA/accB alternate so iter k's min-drain overlaps iter k+1's MFMAs,
// breaking the MFMA->accvgpr_read->min->WAR serial tail.
__global__ __launch_bounds__(256, 3) void knn_kernel(
    const ushort_t* __restrict__ Qb, const ushort_t* __restrict__ Kb,
    unsigned* __restrict__ rminb) {
  int b = blockIdx.x;
  int lin = (b & 7) * 114 + (b >> 3);   // bijective: 912 = 8*114
  int ns = lin / 228, rowblk = lin - ns * 228;
  int brow = rowblk * 64;
  int lane = threadIdx.x & 63;
  int w = threadIdx.x >> 6;
  int l15 = lane & 15, l4 = lane >> 4;

  const char* gW = (const char*)Kb + (size_t)(ns * NIT) * TILEB
                   + w * 3072 + lane * 16;
  const char* Aw = (const char*)Qb + (size_t)(brow >> 4) * 3072 + lane * 16;

  bf16x8 af[4][3];
  #pragma unroll
  for (int rt = 0; rt < 4; ++rt)
    #pragma unroll
    for (int ks = 0; ks < 3; ++ks)
      af[rt][ks] = *(const bf16x8*)(Aw + (rt * 3 + ks) * 1024);

  float rmin[4][4];
  #pragma unroll
  for (int rt = 0; rt < 4; ++rt)
    #pragma unroll
    for (int j = 0; j < 4; ++j) rmin[rt][j] = INFINITY;

  const f32x4 fz = {0.f, 0.f, 0.f, 0.f};

  bf16x8 bufA[3], bufB[3];       // B-tile double buffer (named, static)
  f32x4 accA[4], accB[4];        // accumulator double buffer (named, static)

  auto loadB = [&](bf16x8 (&bb)[3], int it) {
    const char* g = gW + (size_t)it * TILEB;
    #pragma unroll
    for (int ks = 0; ks < 3; ++ks)
      bb[ks] = *(const bf16x8*)(g + ks * 1024);
  };

  auto mfmaTo = [&](f32x4 (&acc)[4], const bf16x8 (&bb)[3]) {
    #pragma unroll
    for (int rt = 0; rt < 4; ++rt)
      acc[rt] = __builtin_amdgcn_mfma_f32_16x16x32_bf16(af[rt][0], bb[0], fz, 0, 0, 0);
    #pragma unroll
    for (int ks = 1; ks < 3; ++ks)
      #pragma unroll
      for (int rt = 0; rt < 4; ++rt)
        acc[rt] = __builtin_amdgcn_mfma_f32_16x16x32_bf16(af[rt][ks], bb[ks], acc[rt], 0, 0, 0);
  };

  auto minAcc = [&](const f32x4 (&acc)[4]) {
    #pragma unroll
    for (int rt = 0; rt < 4; ++rt)
      #pragma unroll
      for (int j = 0; j < 4; ++j)
        rmin[rt][j] = fminf(rmin[rt][j], acc[rt][j]);
  };

  loadB(bufA, 0); loadB(bufB, 1);
  mfmaTo(accA, bufA);            // iter 0 MFMAs
  loadB(bufA, 2);

  // steady state: mfma of iter k+1 issues BEFORE min of iter k
  int k = 0;
  #pragma unroll 1
  for (int tri = 0; tri < 27; ++tri, k += 2) {
    mfmaTo(accB, bufB); minAcc(accA); loadB(bufB, k + 3);
    mfmaTo(accA, bufA); minAcc(accB); loadB(bufA, k + 4);
  }
  // k == 54: mfma'd 0..54, min'd 0..53; bufB = it55, bufA = it56
  mfmaTo(accB, bufB); minAcc(accA);   // mfma 55, min 54
  mfmaTo(accA, bufA); minAcc(accB);   // mfma 56, min 55
  minAcc(accA);                        // min 56

  // min over the 16 key-cols (l15 lanes), then device atomicMin per row
  #pragma unroll
  for (int rt = 0; rt < 4; ++rt)
    #pragma unroll
    for (int j = 0; j < 4; ++j) {
      float m = rmin[rt][j];
      m = fminf(m, __shfl_xor(m, 1, 64));
      m = fminf(m, __shfl_xor(m, 2, 64));
      m = fminf(m, __shfl_xor(m, 4, 64));
      m = fminf(m, __shfl_xor(m, 8, 64));
      if (l15 == 0) {
        unsigned bu = __float_as_uint(m);
        unsigned tu = bu ^ (unsigned)(((int)bu >> 31) | (int)0x80000000);
        atomicMin(&rminb[brow + rt * 16 + l4 * 4 + j], tu);
      }
    }
}

// ------ final stage 1: decode + add qn, per-block partial sums ------------
__global__ __launch_bounds__(64) void final1_kernel(
    const unsigned* __restrict__ rminb, const float* __restrict__ qn,
    float* __restrict__ partial) {
  int r = blockIdx.x * 64 + threadIdx.x;   // grid 225 covers 14400 real rows
  unsigned u = rminb[r];
  unsigned bu = (u & 0x80000000u) ? (u ^ 0x80000000u) : ~u;
  float val = __uint_as_float(bu) + qn[r];
  #pragma unroll
  for (int off = 32; off; off >>= 1) val += __shfl_down(val, off, 64);
  if (threadIdx.x == 0) partial[blockIdx.x] = val;
}

// ------ final stage 2: deterministic sum of 225 partials ------------------
__global__ __launch_bounds__(256) void final2_kernel(
    const float* __restrict__ partial, float* __restrict__ out) {
  int t = threadIdx.x;
  float v = (t < 225) ? partial[t] : 0.f;
  #pragma unroll
  for (int off = 32; off; off >>= 1) v += __shfl_down(v, off, 64);
  __shared__ float s[4];
  if ((t & 63) == 0) s[t >> 6] = v;
  __syncthreads();
  if (t == 0) out[0] = s[0] + s[1] + s[2] + s[3];
}

extern "C" void kernel_launch(void* const* d_in, const int* in_sizes, int n_in,
                              void* d_out, int out_size, void* d_ws, size_t ws_size,
                              hipStream_t stream) {
  const float* resv = (const float*)d_in[0];
  const float* valv = (const float*)d_in[1];
  char* ws = (char*)d_ws;
  ushort_t* Qb      = (ushort_t*)ws;                 // 2,801,664 B (14592 rows)
  ushort_t* Kb      = (ushort_t*)(ws + 2801664);     // 2,801,664 B (14592 cols)
  float* qn         = (float*)(ws + 5603328);        //    58,368 B
  unsigned* rminb   = (unsigned*)(ws + 5661696);     //    58,368 B
  float* partial    = (float*)(ws + 5720064);        //       900 B
  float* out = (float*)d_out;

  prep_kernel<<<7296, 256, 0, stream>>>(resv, valv, Qb, Kb, qn, rminb);
  knn_kernel<<<912, 256, 0, stream>>>(Qb, Kb, rminb);
  final1_kernel<<<225, 64, 0, stream>>>(rminb, qn, partial);
  final2_kernel<<<1, 256, 0, stream>>>(partial, out);
}

// Round 17
// 53.186 us; speedup vs baseline: 1.0917x; 1.0588x over previous
//
#include <hip/hip_runtime.h>
#include <hip/hip_bf16.h>
#include <math.h>

typedef __attribute__((ext_vector_type(8))) short bf16x8;
typedef __attribute__((ext_vector_type(4))) float f32x4;
typedef unsigned short ushort_t;

#define NP 14400     // real patches per video
#define NPK 14592    // padded rows/cols (228 groups of 64; 912 groups of 16)
#define NSEG 16      // column segments (912 cols = 57 groups of 16 each)
#define NIT 57       // 16-col groups per segment
#define GRPB 3072    // bytes per 16-col group (16 cols * 96 k * 2B)

__device__ __forceinline__ ushort_t f2bf(float f) {
  unsigned u = __float_as_uint(f);
  u += 0x7FFF + ((u >> 16) & 1);   // RNE
  return (ushort_t)(u >> 16);
}
__device__ __forceinline__ float bf2f(ushort_t b) {
  return __uint_as_float(((unsigned)b) << 16);
}

// Fragment-order layouts (16B chunks laid out so consumer reads are
// base + lane*16 + imm — fully coalesced, conflict-free):
// K: chunk = ((p>>6)*12 + ((p>>4)&3)*3 + (d>>5))*64 + ((d>>3)&3)*16 + (p&15)
//    (16-col group g occupies bytes [g*3072, (g+1)*3072))
// Q: chunk = ((p>>4)*3 + (d>>5))*64 + ((d>>3)&3)*16 + (p&15)
__device__ __forceinline__ size_t kidx(int p, int d) {
  return ((size_t)(((p >> 6) * 12 + ((p >> 4) & 3) * 3 + (d >> 5)) * 64
          + ((d >> 3) & 3) * 16 + (p & 15))) * 8 + (d & 7);
}
__device__ __forceinline__ size_t qidx(int p, int d) {
  return ((size_t)(((p >> 4) * 3 + (d >> 5)) * 64
          + ((d >> 3) & 3) * 16 + (p & 15))) * 8 + (d & 7);
}

// ---------------- prep: patches -> bf16 in fragment order -----------------
// Q: slots 0..74 = bf16(-2*q), 75,76 = 1.0, rest 0; qn = fp32 norm.
// K: slots 0..74 = bf16(k), 75 = bf16(kn), 76 = bf16(kn residual), rest 0.
// Pad rows/cols (p >= NP): Q pad = zeros (qn=0); K pad = zero data with
// norm slot 3.39e38 (never wins the min).
__global__ __launch_bounds__(256) void prep_kernel(
    const float* __restrict__ resv, const float* __restrict__ valv,
    ushort_t* __restrict__ Qb, ushort_t* __restrict__ Kb,
    float* __restrict__ qn, unsigned* __restrict__ rminb) {
  int w = threadIdx.x >> 6;
  int lane = threadIdx.x & 63;
  int pg = blockIdx.x * 4 + w;          // 0..29183
  int isK = pg >= NPK;
  int p = isK ? pg - NPK : pg;          // 0..14591

  if (p >= NP) {                        // pad row/col
    if (isK) {
      Kb[kidx(p, lane)] = 0;
      if (lane < 32)
        Kb[kidx(p, lane + 64)] = (lane == 11) ? (ushort_t)0x7F7F : (ushort_t)0;
    } else {
      Qb[qidx(p, lane)] = 0;
      if (lane < 32) Qb[qidx(p, lane + 64)] = 0;
      if (lane == 0) { qn[p] = 0.f; rminb[p] = 0xFFFFFFFFu; }
    }
    return;
  }

  const float* src = isK ? valv : resv;
  int t = p / 3600; int rem = p - t * 3600;
  int y = rem / 60;  int x = rem - y * 60;

  float v0, v1 = 0.f;
  {
    int d = lane;  // < 75 always
    int c = d / 25; int r = d - c * 25; int dy = r / 5; int dx = r - dy * 5;
    v0 = src[((c * 4 + t) * 64 + (y + dy)) * 64 + (x + dx)];
  }
  if (lane < 11) {
    int d = lane + 64;
    int c = d / 25; int r = d - c * 25; int dy = r / 5; int dx = r - dy * 5;
    v1 = src[((c * 4 + t) * 64 + (y + dy)) * 64 + (x + dx)];
  }
  ushort_t b0 = f2bf(v0), b1 = f2bf(v1);
  float f0 = bf2f(b0), f1 = bf2f(b1);

  float sq = f0 * f0 + f1 * f1;
  #pragma unroll
  for (int off = 1; off < 64; off <<= 1) sq += __shfl_xor(sq, off, 64);

  if (isK) {
    ushort_t khi = f2bf(sq);
    ushort_t klo = f2bf(sq - bf2f(khi));
    ushort_t s1 = (lane < 11) ? b1
                : (lane == 11 ? khi : (lane == 12 ? klo : (ushort_t)0));
    Kb[kidx(p, lane)] = b0;
    if (lane < 32) Kb[kidx(p, lane + 64)] = s1;
  } else {
    ushort_t s0 = f2bf(-2.f * f0);
    ushort_t s1 = (lane < 11) ? f2bf(-2.f * f1)
                : ((lane == 11 || lane == 12) ? (ushort_t)0x3F80 : (ushort_t)0);
    Qb[qidx(p, lane)] = s0;
    if (lane < 32) Qb[qidx(p, lane + 64)] = s1;
    if (lane == 0) { qn[p] = sq; rminb[p] = 0xFFFFFFFFu; }
  }
}

// ------- main: ONE-WAVE blocks, 64x16 tiles, depth-2 B in VGPRs -----------
// 3648 blocks = 8 x 456 (bijective). XCD x reads segments {2x,2x+1}
// (0.35 MB Kb) + all Qb rows (2.8 MB) -> L2-resident. 1-wave blocks remove
// block-granularity residency quantization: HW packs waves to the register
// limit (~4/SIMD at <=128 regs) and refills piecemeal.
__global__ __launch_bounds__(64, 4) void knn_kernel(
    const ushort_t* __restrict__ Qb, const ushort_t* __restrict__ Kb,
    unsigned* __restrict__ rminb) {
  int b = blockIdx.x;
  int lin = (b & 7) * 456 + (b >> 3);   // bijective: 3648 = 8*456
  int ns = lin / 228, rowblk = lin - ns * 228;
  int brow = rowblk * 64;
  int lane = threadIdx.x;               // 0..63
  int l15 = lane & 15, l4 = lane >> 4;

  // B stream: segment ns = 16-col groups [ns*57, ns*57+57)
  const char* gW = (const char*)Kb + (size_t)(ns * NIT) * GRPB + lane * 16;
  // A: 64 rows x 96 k, fragment-order, lane-contiguous
  const char* Aw = (const char*)Qb + (size_t)(rowblk * 4) * GRPB + lane * 16;

  bf16x8 af[4][3];
  #pragma unroll
  for (int rt = 0; rt < 4; ++rt)
    #pragma unroll
    for (int ks = 0; ks < 3; ++ks)
      af[rt][ks] = *(const bf16x8*)(Aw + (rt * 3 + ks) * 1024);

  float rmin[4][4];
  #pragma unroll
  for (int rt = 0; rt < 4; ++rt)
    #pragma unroll
    for (int j = 0; j < 4; ++j) rmin[rt][j] = INFINITY;

  const f32x4 fz = {0.f, 0.f, 0.f, 0.f};
  bf16x8 bbuf[2][3];                    // depth-2, literal indices only

  auto loadB = [&](int bi, int it) {
    const char* g = gW + (size_t)it * GRPB;
    #pragma unroll
    for (int ks = 0; ks < 3; ++ks)
      bbuf[bi][ks] = *(const bf16x8*)(g + ks * 1024);
  };

  auto compute = [&](int bi) {
    f32x4 acc[4];
    {
      bf16x8 bv = bbuf[bi][0];
      #pragma unroll
      for (int rt = 0; rt < 4; ++rt)
        acc[rt] = __builtin_amdgcn_mfma_f32_16x16x32_bf16(af[rt][0], bv, fz, 0, 0, 0);
    }
    #pragma unroll
    for (int ks = 1; ks < 3; ++ks) {
      bf16x8 bv = bbuf[bi][ks];
      #pragma unroll
      for (int rt = 0; rt < 4; ++rt)
        acc[rt] = __builtin_amdgcn_mfma_f32_16x16x32_bf16(af[rt][ks], bv, acc[rt], 0, 0, 0);
    }
    #pragma unroll
    for (int rt = 0; rt < 4; ++rt)
      #pragma unroll
      for (int j = 0; j < 4; ++j)
        rmin[rt][j] = fminf(rmin[rt][j], acc[rt][j]);
  };

  loadB(0, 0);
  loadB(1, 1);

  // 57 iters: 27 doubles (0..53) + 3-iter tail; loads 2 iters ahead
  int k = 0;
  #pragma unroll 1
  for (int tri = 0; tri < 27; ++tri, k += 2) {
    compute(0); loadB(0, k + 2);
    compute(1); loadB(1, k + 3);
  }
  // k == 54; in flight: (0,54),(1,55)
  compute(0); loadB(0, 56);   // iter 54
  compute(1);                  // iter 55
  compute(0);                  // iter 56

  // min over the 16 key-cols (l15 lanes), then device atomicMin per row
  #pragma unroll
  for (int rt = 0; rt < 4; ++rt)
    #pragma unroll
    for (int j = 0; j < 4; ++j) {
      float m = rmin[rt][j];
      m = fminf(m, __shfl_xor(m, 1, 64));
      m = fminf(m, __shfl_xor(m, 2, 64));
      m = fminf(m, __shfl_xor(m, 4, 64));
      m = fminf(m, __shfl_xor(m, 8, 64));
      if (l15 == 0) {
        unsigned bu = __float_as_uint(m);
        unsigned tu = bu ^ (unsigned)(((int)bu >> 31) | (int)0x80000000);
        atomicMin(&rminb[brow + rt * 16 + l4 * 4 + j], tu);
      }
    }
}

// ------ final stage 1: decode + add qn, per-block partial sums ------------
__global__ __launch_bounds__(64) void final1_kernel(
    const unsigned* __restrict__ rminb, const float* __restrict__ qn,
    float* __restrict__ partial) {
  int r = blockIdx.x * 64 + threadIdx.x;   // grid 225 covers 14400 real rows
  unsigned u = rminb[r];
  unsigned bu = (u & 0x80000000u) ? (u ^ 0x80000000u) : ~u;
  float val = __uint_as_float(bu) + qn[r];
  #pragma unroll
  for (int off = 32; off; off >>= 1) val += __shfl_down(val, off, 64);
  if (threadIdx.x == 0) partial[blockIdx.x] = val;
}

// ------ final stage 2: deterministic sum of 225 partials ------------------
__global__ __launch_bounds__(256) void final2_kernel(
    const float* __restrict__ partial, float* __restrict__ out) {
  int t = threadIdx.x;
  float v = (t < 225) ? partial[t] : 0.f;
  #pragma unroll
  for (int off = 32; off; off >>= 1) v += __shfl_down(v, off, 64);
  __shared__ float s[4];
  if ((t & 63) == 0) s[t >> 6] = v;
  __syncthreads();
  if (t == 0) out[0] = s[0] + s[1] + s[2] + s[3];
}

extern "C" void kernel_launch(void* const* d_in, const int* in_sizes, int n_in,
                              void* d_out, int out_size, void* d_ws, size_t ws_size,
                              hipStream_t stream) {
  const float* resv = (const float*)d_in[0];
  const float* valv = (const float*)d_in[1];
  char* ws = (char*)d_ws;
  ushort_t* Qb      = (ushort_t*)ws;                 // 2,801,664 B (14592 rows)
  ushort_t* Kb      = (ushort_t*)(ws + 2801664);     // 2,801,664 B (14592 cols)
  float* qn         = (float*)(ws + 5603328);        //    58,368 B
  unsigned* rminb   = (unsigned*)(ws + 5661696);     //    58,368 B
  float* partial    = (float*)(ws + 5720064);        //       900 B
  float* out = (float*)d_out;

  prep_kernel<<<7296, 256, 0, stream>>>(resv, valv, Qb, Kb, qn, rminb);
  knn_kernel<<<3648, 64, 0, stream>>>(Qb, Kb, rminb);
  final1_kernel<<<225, 64, 0, stream>>>(rminb, qn, partial);
  final2_kernel<<<1, 256, 0, stream>>>(partial, out);
}

// Round 20
// 49.444 us; speedup vs baseline: 1.1744x; 1.0757x over previous
//
#include <hip/hip_runtime.h>
#include <hip/hip_bf16.h>
#include <math.h>

typedef __attribute__((ext_vector_type(4))) float f32x4;
typedef __attribute__((ext_vector_type(2))) long long2_t;

#define NP 14400     // real patches per video
#define NPK 14592    // padded rows/cols (912 groups of 16)
#define NSEG 16      // column segments (912 cols = 57 groups of 16 each)
#define NIT 57       // 16-col groups per segment
#define GRPB 1536    // bytes per 16-col fp8 group (16 cols * 96 k * 1B)

// ---- manual OCP e4m3fn encode/decode (RNE, saturating; prep-only cost) ----
__device__ __forceinline__ unsigned char f2fp8(float x) {
  unsigned u = __float_as_uint(x);
  unsigned sign = (u >> 31) << 7;
  int exp = (int)((u >> 23) & 0xFF) - 127;
  unsigned man = u & 0x7FFFFF;
  if (exp >= -6) {
    unsigned keep = man >> 20;
    unsigned rest = man & 0xFFFFF;
    keep += (rest > 0x80000u) || (rest == 0x80000u && (keep & 1));
    int e8 = exp + 7;
    if (keep == 8) { keep = 0; e8 += 1; }
    if (e8 > 15 || (e8 == 15 && keep == 7)) return sign | 0x7E;  // sat 448
    return sign | ((unsigned)e8 << 3) | keep;
  } else {
    float a = fabsf(x);
    int q = (int)(a * 512.f + 0.5f);       // subnormal step 2^-9
    if (q >= 8) return sign | 0x08;        // rounds up to 2^-6
    return sign | (unsigned)q;
  }
}
__device__ __forceinline__ float fp82f(unsigned char b) {
  unsigned e = (b >> 3) & 15, m = b & 7;
  float v = (e == 0) ? ldexpf((float)m, -9) : ldexpf((float)(8 + m), (int)e - 10);
  return (b & 0x80) ? -v : v;
}

// fp8 fragment-order address for element (p = row/col index, d = k index):
// lane = (p&15) + 16*((d&31)>>3), k-chunk ks = d>>5, byte e7 = d&7.
// Group (p>>4) is 1536 B: [0,1024) = ks0/ks1 interleaved 8B halves per lane
// (16B/lane dwordx4 load), [1024,1536) = ks2 (8B/lane dwordx2 load).
__device__ __forceinline__ size_t f8idx(int p, int d) {
  int g = p >> 4, c = p & 15, ks = d >> 5, l4e = (d & 31) >> 3, e7 = d & 7;
  size_t base = (size_t)g * GRPB;
  if (ks < 2) return base + (size_t)((c + 16 * l4e) * 16 + ks * 8 + e7);
  return base + 1024 + (size_t)((c + 16 * l4e) * 8 + e7);
}

// ---------------- prep: patches -> fp8 in fragment order ------------------
// Q: slots 0..74 = fp8(-2*q), 75..95 = 0; qn = fp32 exact norm of q.
// K: slots 0..74 = fp8(k), 75..95 = 0;  kn = fp32 norm of fp8-decoded k.
// Pad rows/cols (p >= NP): zero data; kn = 3.39e38 (never wins); qn = 0.
__global__ __launch_bounds__(256) void prep_kernel(
    const float* __restrict__ resv, const float* __restrict__ valv,
    unsigned char* __restrict__ Qb, unsigned char* __restrict__ Kb,
    float* __restrict__ qn, float* __restrict__ kn,
    unsigned* __restrict__ rminb) {
  int w = threadIdx.x >> 6;
  int lane = threadIdx.x & 63;
  int pg = blockIdx.x * 4 + w;          // 0..29183
  int isK = pg >= NPK;
  int p = isK ? pg - NPK : pg;          // 0..14591

  float v0 = 0.f, v1 = 0.f;
  if (p < NP) {
    const float* src = isK ? valv : resv;
    int t = p / 3600; int rem = p - t * 3600;
    int y = rem / 60;  int x = rem - y * 60;
    {
      int d = lane;  // < 75 always
      int c = d / 25; int r = d - c * 25; int dy = r / 5; int dx = r - dy * 5;
      v0 = src[((c * 4 + t) * 64 + (y + dy)) * 64 + (x + dx)];
    }
    if (lane < 11) {
      int d = lane + 64;
      int c = d / 25; int r = d - c * 25; int dy = r / 5; int dx = r - dy * 5;
      v1 = src[((c * 4 + t) * 64 + (y + dy)) * 64 + (x + dx)];
    }
  }

  unsigned char b0, b1;
  if (isK) { b0 = f2fp8(v0); b1 = f2fp8(v1); }
  else     { b0 = f2fp8(-2.f * v0); b1 = f2fp8(-2.f * v1); }

  float sq;
  if (isK) {
    float d0 = fp82f(b0), d1 = fp82f(b1);   // norm of quantized keys
    sq = d0 * d0 + d1 * d1;
  } else {
    sq = v0 * v0 + v1 * v1;                 // exact query norm
  }
  #pragma unroll
  for (int off = 1; off < 64; off <<= 1) sq += __shfl_xor(sq, off, 64);

  unsigned char* dst = isK ? Kb : Qb;
  dst[f8idx(p, lane)] = b0;
  if (lane < 32) dst[f8idx(p, lane + 64)] = b1;
  if (lane == 0) {
    if (isK) kn[p] = (p < NP) ? sq : 3.39e38f;
    else { qn[p] = sq; rminb[p] = 0xFFFFFFFFu; }
  }
}

// ------- main: ONE-WAVE blocks, 64x16 tiles, fp8 MFMA, depth-2 ------------
// Identical structure to the bf16 R17 kernel; only dtype/layout changed:
// 1536 B of B-operand per wave-iter (half of bf16) at the same MFMA rate.
// kn folded in via the MFMA C-operand (prefetched with the B tile).
__global__ __launch_bounds__(64, 4) void knn_kernel(
    const unsigned char* __restrict__ Qb, const unsigned char* __restrict__ Kb,
    const float* __restrict__ kn, unsigned* __restrict__ rminb) {
  int b = blockIdx.x;
  int lin = (b & 7) * 456 + (b >> 3);   // bijective: 3648 = 8*456
  int ns = lin / 228, rowblk = lin - ns * 228;
  int brow = rowblk * 64;
  int lane = threadIdx.x;               // 0..63
  int l15 = lane & 15, l4 = lane >> 4;

  const char* gW = (const char*)Kb + (size_t)(ns * NIT) * GRPB;
  const char* Aw = (const char*)Qb + (size_t)(rowblk * 4) * GRPB;
  int colbase = ns * 912 + l15;

  // A fragments: 64 rows x 96 k (4 rowtiles x 3 k-chunks), 2 VGPR each
  long af01[4][2]; long af2[4];
  #pragma unroll
  for (int rt = 0; rt < 4; ++rt) {
    long2_t t = *(const long2_t*)(Aw + rt * GRPB + lane * 16);
    af01[rt][0] = t[0]; af01[rt][1] = t[1];
    af2[rt] = *(const long*)(Aw + rt * GRPB + 1024 + lane * 8);
  }

  float rmin[4][4];
  #pragma unroll
  for (int rt = 0; rt < 4; ++rt)
    #pragma unroll
    for (int j = 0; j < 4; ++j) rmin[rt][j] = INFINITY;

  long2_t b01[2]; long b2[2]; float kvb[2];   // depth-2, literal indices

  auto loadB = [&](int bi, int it) {
    const char* g = gW + (size_t)it * GRPB;
    b01[bi] = *(const long2_t*)(g + lane * 16);
    b2[bi]  = *(const long*)(g + 1024 + lane * 8);
    kvb[bi] = kn[colbase + it * 16];
  };

  auto compute = [&](int bi) {
    float kv = kvb[bi];
    f32x4 ci = {kv, kv, kv, kv};
    f32x4 acc[4];
    {
      long bv = b01[bi][0];
      #pragma unroll
      for (int rt = 0; rt < 4; ++rt)
        acc[rt] = __builtin_amdgcn_mfma_f32_16x16x32_fp8_fp8(
            af01[rt][0], bv, ci, 0, 0, 0);
    }
    {
      long bv = b01[bi][1];
      #pragma unroll
      for (int rt = 0; rt < 4; ++rt)
        acc[rt] = __builtin_amdgcn_mfma_f32_16x16x32_fp8_fp8(
            af01[rt][1], bv, acc[rt], 0, 0, 0);
    }
    {
      long bv = b2[bi];
      #pragma unroll
      for (int rt = 0; rt < 4; ++rt)
        acc[rt] = __builtin_amdgcn_mfma_f32_16x16x32_fp8_fp8(
            af2[rt], bv, acc[rt], 0, 0, 0);
    }
    #pragma unroll
    for (int rt = 0; rt < 4; ++rt)
      #pragma unroll
      for (int j = 0; j < 4; ++j)
        rmin[rt][j] = fminf(rmin[rt][j], acc[rt][j]);
  };

  loadB(0, 0);
  loadB(1, 1);

  // 57 iters: 27 doubles (0..53) + 3-iter tail; loads 2 iters ahead
  int k = 0;
  #pragma unroll 1
  for (int tri = 0; tri < 27; ++tri, k += 2) {
    compute(0); loadB(0, k + 2);
    compute(1); loadB(1, k + 3);
  }
  // k == 54; in flight: (0,54),(1,55)
  compute(0); loadB(0, 56);   // iter 54
  compute(1);                  // iter 55
  compute(0);                  // iter 56

  // min over the 16 key-cols (l15 lanes), then device atomicMin per row
  #pragma unroll
  for (int rt = 0; rt < 4; ++rt)
    #pragma unroll
    for (int j = 0; j < 4; ++j) {
      float m = rmin[rt][j];
      m = fminf(m, __shfl_xor(m, 1, 64));
      m = fminf(m, __shfl_xor(m, 2, 64));
      m = fminf(m, __shfl_xor(m, 4, 64));
      m = fminf(m, __shfl_xor(m, 8, 64));
      if (l15 == 0) {
        unsigned bu = __float_as_uint(m);
        unsigned tu = bu ^ (unsigned)(((int)bu >> 31) | (int)0x80000000);
        atomicMin(&rminb[brow + rt * 16 + l4 * 4 + j], tu);
      }
    }
}

// ------ final stage 1: decode + add qn, per-block partial sums ------------
__global__ __launch_bounds__(64) void final1_kernel(
    const unsigned* __restrict__ rminb, const float* __restrict__ qn,
    float* __restrict__ partial) {
  int r = blockIdx.x * 64 + threadIdx.x;   // grid 225 covers 14400 real rows
  unsigned u = rminb[r];
  unsigned bu = (u & 0x80000000u) ? (u ^ 0x80000000u) : ~u;
  float val = __uint_as_float(bu) + qn[r];
  #pragma unroll
  for (int off = 32; off; off >>= 1) val += __shfl_down(val, off, 64);
  if (threadIdx.x == 0) partial[blockIdx.x] = val;
}

// ------ final stage 2: deterministic sum of 225 partials ------------------
__global__ __launch_bounds__(256) void final2_kernel(
    const float* __restrict__ partial, float* __restrict__ out) {
  int t = threadIdx.x;
  float v = (t < 225) ? partial[t] : 0.f;
  #pragma unroll
  for (int off = 32; off; off >>= 1) v += __shfl_down(v, off, 64);
  __shared__ float s[4];
  if ((t & 63) == 0) s[t >> 6] = v;
  __syncthreads();
  if (t == 0) out[0] = s[0] + s[1] + s[2] + s[3];
}

extern "C" void kernel_launch(void* const* d_in, const int* in_sizes, int n_in,
                              void* d_out, int out_size, void* d_ws, size_t ws_size,
                              hipStream_t stream) {
  const float* resv = (const float*)d_in[0];
  const float* valv = (const float*)d_in[1];
  char* ws = (char*)d_ws;
  unsigned char* Qb = (unsigned char*)ws;            // 1,400,832 B
  unsigned char* Kb = (unsigned char*)(ws + 1400832);// 1,400,832 B
  float* qn         = (float*)(ws + 2801664);        //    58,368 B
  float* kn         = (float*)(ws + 2860032);        //    58,368 B
  unsigned* rminb   = (unsigned*)(ws + 2918400);     //    58,368 B
  float* partial    = (float*)(ws + 2976768);        //       900 B
  float* out = (float*)d_out;

  prep_kernel<<<7296, 256, 0, stream>>>(resv, valv, Qb, Kb, qn, kn, rminb);
  knn_kernel<<<3648, 64, 0, stream>>>(Qb, Kb, kn, rminb);
  final1_kernel<<<225, 64, 0, stream>>>(rminb, qn, partial);
  final2_kernel<<<1, 256, 0, stream>>>(partial, out);
}

// Round 23
// 46.586 us; speedup vs baseline: 1.2464x; 1.0614x over previous
//
#include <hip/hip_runtime.h>
#include <math.h>

typedef __attribute__((ext_vector_type(4))) float f32x4;
typedef __attribute__((ext_vector_type(8))) int int8v;

#define NP 14400     // real patches per video
#define NPK 14592    // padded rows/cols (912 groups of 16)
#define NSEG 16      // column segments (912 col-groups = 57 per segment)
#define NIT 57       // 16-col groups per segment
#define GRPB 2048    // bytes per 16-col group (16 cols * 128 k * 1B, K padded)

// ---- manual OCP e4m3fn encode/decode (RNE, saturating; prep-only cost) ----
__device__ __forceinline__ unsigned char f2fp8(float x) {
  unsigned u = __float_as_uint(x);
  unsigned sign = (u >> 31) << 7;
  int exp = (int)((u >> 23) & 0xFF) - 127;
  unsigned man = u & 0x7FFFFF;
  if (exp >= -6) {
    unsigned keep = man >> 20;
    unsigned rest = man & 0xFFFFF;
    keep += (rest > 0x80000u) || (rest == 0x80000u && (keep & 1));
    int e8 = exp + 7;
    if (keep == 8) { keep = 0; e8 += 1; }
    if (e8 > 15 || (e8 == 15 && keep == 7)) return sign | 0x7E;  // sat 448
    return sign | ((unsigned)e8 << 3) | keep;
  } else {
    float a = fabsf(x);
    int q = (int)(a * 512.f + 0.5f);       // subnormal step 2^-9
    if (q >= 8) return sign | 0x08;        // rounds up to 2^-6
    return sign | (unsigned)q;
  }
}
__device__ __forceinline__ float fp82f(unsigned char b) {
  unsigned e = (b >> 3) & 15, m = b & 7;
  float v = (e == 0) ? ldexpf((float)m, -9) : ldexpf((float)(8 + m), (int)e - 10);
  return (b & 0x80) ? -v : v;
}

// MX fragment layout (K=128): group g = p>>4 is 2048 B; element (p,d) at
// g*2048 + ((p&15) + 16*(d>>5))*32 + (d&31). MFMA lane l holds idx = l&15,
// k-group = l>>4 (32 contiguous k bytes) -> lane byte base = l*32.
// A and B use the SAME mapping, so any within-slot k-permutation cancels.
__device__ __forceinline__ size_t f8idx(int p, int d) {
  return (size_t)(p >> 4) * GRPB
       + (size_t)((((p & 15) + 16 * (d >> 5)) * 32) + (d & 31));
}

// ---------------- prep: patches -> fp8 in MX fragment order ---------------
// Q: k 0..74 = fp8(-2*q), 75..127 = 0; qn = fp32 exact norm.
// K: k 0..74 = fp8(k), 75..127 = 0;   kn = fp32 norm of fp8-decoded k.
// Pad rows/cols (p >= NP): zero data; kn = 3.39e38 (never wins); qn = 0.
__global__ __launch_bounds__(256) void prep_kernel(
    const float* __restrict__ resv, const float* __restrict__ valv,
    unsigned char* __restrict__ Qb, unsigned char* __restrict__ Kb,
    float* __restrict__ qn, float* __restrict__ kn,
    unsigned* __restrict__ rminb) {
  int w = threadIdx.x >> 6;
  int lane = threadIdx.x & 63;
  int pg = blockIdx.x * 4 + w;          // 0..29183
  int isK = pg >= NPK;
  int p = isK ? pg - NPK : pg;          // 0..14591

  float v0 = 0.f, v1 = 0.f;
  if (p < NP) {
    const float* src = isK ? valv : resv;
    int t = p / 3600; int rem = p - t * 3600;
    int y = rem / 60;  int x = rem - y * 60;
    {
      int d = lane;  // < 75 always
      int c = d / 25; int r = d - c * 25; int dy = r / 5; int dx = r - dy * 5;
      v0 = src[((c * 4 + t) * 64 + (y + dy)) * 64 + (x + dx)];
    }
    if (lane < 11) {
      int d = lane + 64;
      int c = d / 25; int r = d - c * 25; int dy = r / 5; int dx = r - dy * 5;
      v1 = src[((c * 4 + t) * 64 + (y + dy)) * 64 + (x + dx)];
    }
  }

  unsigned char b0, b1;
  if (isK) { b0 = f2fp8(v0); b1 = f2fp8(v1); }
  else     { b0 = f2fp8(-2.f * v0); b1 = f2fp8(-2.f * v1); }

  float sq;
  if (isK) {
    float d0 = fp82f(b0), d1 = fp82f(b1);   // norm of quantized keys
    sq = d0 * d0 + d1 * d1;
  } else {
    sq = v0 * v0 + v1 * v1;                 // exact query norm
  }
  #pragma unroll
  for (int off = 1; off < 64; off <<= 1) sq += __shfl_xor(sq, off, 64);

  unsigned char* dst = isK ? Kb : Qb;
  dst[f8idx(p, lane)] = b0;                     // k-groups 0,1
  if (lane < 32) {
    dst[f8idx(p, lane + 64)] = b1;              // k-group 2 (k 64..95)
  } else {
    // zero k-group 3 (k 96..127): slot base ((p&15)+48)*32
    dst[(size_t)(p >> 4) * GRPB
        + (size_t)((((p & 15) + 48) * 32) + (lane - 32))] = 0;
  }
  if (lane == 0) {
    if (isK) kn[p] = (p < NP) ? sq : 3.39e38f;
    else { qn[p] = sq; rminb[p] = 0xFFFFFFFFu; }
  }
}

// ------- main: ONE-WAVE blocks, 64x16 tiles, MX-scaled fp8 K=128 ----------
// 3648 blocks = 8 x 456 (bijective). 4 MFMAs/iter (one 16x16x128 per
// row-tile, scales = 1.0), kn folded via the C operand. Depth-2 B regs.
__global__ __launch_bounds__(64, 4) void knn_kernel(
    const unsigned char* __restrict__ Qb, const unsigned char* __restrict__ Kb,
    const float* __restrict__ kn, unsigned* __restrict__ rminb) {
  int b = blockIdx.x;
  int lin = (b & 7) * 456 + (b >> 3);   // bijective: 3648 = 8*456
  int ns = lin / 228, rowblk = lin - ns * 228;
  int brow = rowblk * 64;
  int lane = threadIdx.x;               // 0..63
  int l15 = lane & 15, l4 = lane >> 4;

  const char* gW = (const char*)Kb + (size_t)(ns * NIT) * GRPB + lane * 32;
  const char* Aw = (const char*)Qb + (size_t)(rowblk * 4) * GRPB + lane * 32;
  int colbase = ns * 912 + l15;

  // A fragments: 64 rows x 128 k = 4 row-tiles x 8 VGPR (32 B/lane)
  int8v af[4];
  #pragma unroll
  for (int rt = 0; rt < 4; ++rt)
    af[rt] = *(const int8v*)(Aw + rt * GRPB);

  float rmin[4][4];
  #pragma unroll
  for (int rt = 0; rt < 4; ++rt)
    #pragma unroll
    for (int j = 0; j < 4; ++j) rmin[rt][j] = INFINITY;

  int8v bbuf[2]; float kvb[2];          // depth-2, literal indices only

  auto loadB = [&](int bi, int it) {
    bbuf[bi] = *(const int8v*)(gW + (size_t)it * GRPB);
    kvb[bi] = kn[colbase + it * 16];
  };

  auto compute = [&](int bi) {
    float kv = kvb[bi];
    f32x4 ci = {kv, kv, kv, kv};
    f32x4 acc[4];
    #pragma unroll
    for (int rt = 0; rt < 4; ++rt)
      acc[rt] = __builtin_amdgcn_mfma_scale_f32_16x16x128_f8f6f4(
          af[rt], bbuf[bi], ci, 0, 0,               // cbsz=0 blgp=0: e4m3
          0, 0x7F7F7F7F, 0, 0x7F7F7F7F);            // scales = 1.0 (e8m0 127)
    #pragma unroll
    for (int rt = 0; rt < 4; ++rt)
      #pragma unroll
      for (int j = 0; j < 4; ++j)
        rmin[rt][j] = fminf(rmin[rt][j], acc[rt][j]);
  };

  loadB(0, 0);
  loadB(1, 1);

  // 57 iters: 27 doubles (0..53) + 3-iter tail; loads 2 iters ahead
  int k = 0;
  #pragma unroll 1
  for (int tri = 0; tri < 27; ++tri, k += 2) {
    compute(0); loadB(0, k + 2);
    compute(1); loadB(1, k + 3);
  }
  // k == 54; in flight: (0,54),(1,55)
  compute(0); loadB(0, 56);   // iter 54
  compute(1);                  // iter 55
  compute(0);                  // iter 56

  // min over the 16 key-cols (l15 lanes), then device atomicMin per row
  #pragma unroll
  for (int rt = 0; rt < 4; ++rt)
    #pragma unroll
    for (int j = 0; j < 4; ++j) {
      float m = rmin[rt][j];
      m = fminf(m, __shfl_xor(m, 1, 64));
      m = fminf(m, __shfl_xor(m, 2, 64));
      m = fminf(m, __shfl_xor(m, 4, 64));
      m = fminf(m, __shfl_xor(m, 8, 64));
      if (l15 == 0) {
        unsigned bu = __float_as_uint(m);
        unsigned tu = bu ^ (unsigned)(((int)bu >> 31) | (int)0x80000000);
        atomicMin(&rminb[brow + rt * 16 + l4 * 4 + j], tu);
      }
    }
}

// ------ final: decode + add qn + deterministic sum (one block) ------------
__global__ __launch_bounds__(1024) void final_kernel(
    const unsigned* __restrict__ rminb, const float* __restrict__ qn,
    float* __restrict__ out) {
  int t = threadIdx.x;
  float s = 0.f;
  for (int i = t; i < NP; i += 1024) {
    unsigned u = rminb[i];
    unsigned bu = (u & 0x80000000u) ? (u ^ 0x80000000u) : ~u;
    s += __uint_as_float(bu) + qn[i];
  }
  #pragma unroll
  for (int off = 32; off; off >>= 1) s += __shfl_down(s, off, 64);
  __shared__ float red[16];
  if ((t & 63) == 0) red[t >> 6] = s;
  __syncthreads();
  if (t == 0) {
    float tot = 0.f;
    #pragma unroll
    for (int i2 = 0; i2 < 16; ++i2) tot += red[i2];
    out[0] = tot;
  }
}

extern "C" void kernel_launch(void* const* d_in, const int* in_sizes, int n_in,
                              void* d_out, int out_size, void* d_ws, size_t ws_size,
                              hipStream_t stream) {
  const float* resv = (const float*)d_in[0];
  const float* valv = (const float*)d_in[1];
  char* ws = (char*)d_ws;
  unsigned char* Qb = (unsigned char*)ws;            // 1,867,776 B
  unsigned char* Kb = (unsigned char*)(ws + 1867776);// 1,867,776 B
  float* qn         = (float*)(ws + 3735552);        //    58,368 B
  float* kn         = (float*)(ws + 3793920);        //    58,368 B
  unsigned* rminb   = (unsigned*)(ws + 3852288);     //    58,368 B
  float* out = (float*)d_out;

  prep_kernel<<<7296, 256, 0, stream>>>(resv, valv, Qb, Kb, qn, kn, rminb);
  knn_kernel<<<3648, 64, 0, stream>>>(Qb, Kb, kn, rminb);
  final_kernel<<<1, 1024, 0, stream>>>(rminb, qn, out);
}

// Round 24
// 44.541 us; speedup vs baseline: 1.3036x; 1.0459x over previous
//
#include <hip/hip_runtime.h>
#include <math.h>

typedef __attribute__((ext_vector_type(4))) float f32x4;
typedef __attribute__((ext_vector_type(8))) int int8v;

#define NP 14400     // real patches per video
#define NPK 14592    // padded rows/cols (912 groups of 16)
#define NSEG 16      // column segments (912 col-groups = 57 per segment)
#define NIT 57       // 16-col groups per segment
#define GRPB 1536    // bytes per 16-col group (16 cols * 96 k * 1B)

// ---- manual OCP e4m3fn encode/decode (RNE, saturating; prep-only cost) ----
__device__ __forceinline__ unsigned char f2fp8(float x) {
  unsigned u = __float_as_uint(x);
  unsigned sign = (u >> 31) << 7;
  int exp = (int)((u >> 23) & 0xFF) - 127;
  unsigned man = u & 0x7FFFFF;
  if (exp >= -6) {
    unsigned keep = man >> 20;
    unsigned rest = man & 0xFFFFF;
    keep += (rest > 0x80000u) || (rest == 0x80000u && (keep & 1));
    int e8 = exp + 7;
    if (keep == 8) { keep = 0; e8 += 1; }
    if (e8 > 15 || (e8 == 15 && keep == 7)) return sign | 0x7E;  // sat 448
    return sign | ((unsigned)e8 << 3) | keep;
  } else {
    float a = fabsf(x);
    int q = (int)(a * 512.f + 0.5f);       // subnormal step 2^-9
    if (q >= 8) return sign | 0x08;        // rounds up to 2^-6
    return sign | (unsigned)q;
  }
}
__device__ __forceinline__ float fp82f(unsigned char b) {
  unsigned e = (b >> 3) & 15, m = b & 7;
  float v = (e == 0) ? ldexpf((float)m, -9) : ldexpf((float)(8 + m), (int)e - 10);
  return (b & 0x80) ? -v : v;
}

// MX fragment layout, 96 real k bytes per column: group g = p>>4 is 1536 B;
// element (p,d) d<96 at g*1536 + ((p&15) + 16*(d>>5))*32 + (d&31).
// MFMA lane l holds idx=l&15, k-group=l>>4 (32 k bytes). Lanes 0..47 load
// their own bytes; lanes 48..63 (k-group 3) RE-READ k-group 2's bytes and
// the A operand for those lanes is zeroed -> group-3 products are exactly 0.
__device__ __forceinline__ size_t f8idx(int p, int d) {
  return (size_t)(p >> 4) * GRPB
       + (size_t)((((p & 15) + 16 * (d >> 5)) * 32) + (d & 31));
}

// ---------------- prep: patches -> fp8 in MX fragment order ---------------
// Q: k 0..74 = fp8(-2*q), 75..95 = 0; qn = fp32 exact norm.
// K: k 0..74 = fp8(k), 75..95 = 0;   kn = fp32 norm of fp8-decoded k.
// Pad rows/cols (p >= NP): zero data; kn = 3.39e38 (never wins); qn = 0.
__global__ __launch_bounds__(256) void prep_kernel(
    const float* __restrict__ resv, const float* __restrict__ valv,
    unsigned char* __restrict__ Qb, unsigned char* __restrict__ Kb,
    float* __restrict__ qn, float* __restrict__ kn,
    unsigned* __restrict__ rminb) {
  int w = threadIdx.x >> 6;
  int lane = threadIdx.x & 63;
  int pg = blockIdx.x * 4 + w;          // 0..29183
  int isK = pg >= NPK;
  int p = isK ? pg - NPK : pg;          // 0..14591

  float v0 = 0.f, v1 = 0.f;
  if (p < NP) {
    const float* src = isK ? valv : resv;
    int t = p / 3600; int rem = p - t * 3600;
    int y = rem / 60;  int x = rem - y * 60;
    {
      int d = lane;  // < 75 always
      int c = d / 25; int r = d - c * 25; int dy = r / 5; int dx = r - dy * 5;
      v0 = src[((c * 4 + t) * 64 + (y + dy)) * 64 + (x + dx)];
    }
    if (lane < 11) {
      int d = lane + 64;
      int c = d / 25; int r = d - c * 25; int dy = r / 5; int dx = r - dy * 5;
      v1 = src[((c * 4 + t) * 64 + (y + dy)) * 64 + (x + dx)];
    }
  }

  unsigned char b0, b1;
  if (isK) { b0 = f2fp8(v0); b1 = f2fp8(v1); }
  else     { b0 = f2fp8(-2.f * v0); b1 = f2fp8(-2.f * v1); }

  float sq;
  if (isK) {
    float d0 = fp82f(b0), d1 = fp82f(b1);   // norm of quantized keys
    sq = d0 * d0 + d1 * d1;
  } else {
    sq = v0 * v0 + v1 * v1;                 // exact query norm
  }
  #pragma unroll
  for (int off = 1; off < 64; off <<= 1) sq += __shfl_xor(sq, off, 64);

  unsigned char* dst = isK ? Kb : Qb;
  dst[f8idx(p, lane)] = b0;                     // k-groups 0,1 (d 0..63)
  if (lane < 32) dst[f8idx(p, lane + 64)] = b1; // k-group 2 (d 64..95)
  if (lane == 0) {
    if (isK) kn[p] = (p < NP) ? sq : 3.39e38f;
    else { qn[p] = sq; rminb[p] = 0xFFFFFFFFu; }
  }
}

// ------- main: ONE-WAVE blocks, 64x16 tiles, MX-scaled fp8 K=128 ----------
// 3648 blocks = 8 x 456 (bijective). 4 MFMAs/iter (one 16x16x128 per
// row-tile, scales = 1.0), kn folded via the C operand. Depth-2 B regs.
// Only 1536 unique B bytes/iter: lanes 48..63 re-read k-group 2 (their A
// operand is zero, so the duplicated products vanish).
__global__ __launch_bounds__(64, 4) void knn_kernel(
    const unsigned char* __restrict__ Qb, const unsigned char* __restrict__ Kb,
    const float* __restrict__ kn, unsigned* __restrict__ rminb) {
  int b = blockIdx.x;
  int lin = (b & 7) * 456 + (b >> 3);   // bijective: 3648 = 8*456
  int ns = lin / 228, rowblk = lin - ns * 228;
  int brow = rowblk * 64;
  int lane = threadIdx.x;               // 0..63
  int l15 = lane & 15, l4 = lane >> 4;
  int bl = (lane < 48 ? lane : lane - 16) * 32;   // lane byte base, <=1504

  const char* gW = (const char*)Kb + (size_t)(ns * NIT) * GRPB + bl;
  const char* Aw = (const char*)Qb + (size_t)(rowblk * 4) * GRPB + bl;
  int colbase = ns * 912 + l15;

  // A fragments: 64 rows x 96 k = 4 row-tiles x 8 VGPR; lanes>=48 zeroed
  int8v af[4];
  #pragma unroll
  for (int rt = 0; rt < 4; ++rt) {
    int8v t = *(const int8v*)(Aw + rt * GRPB);
    if (lane >= 48) {
      #pragma unroll
      for (int i = 0; i < 8; ++i) t[i] = 0;
    }
    af[rt] = t;
  }

  float rmin[4][4];
  #pragma unroll
  for (int rt = 0; rt < 4; ++rt)
    #pragma unroll
    for (int j = 0; j < 4; ++j) rmin[rt][j] = INFINITY;

  int8v bbuf[2]; float kvb[2];          // depth-2, literal indices only

  auto loadB = [&](int bi, int it) {
    bbuf[bi] = *(const int8v*)(gW + (size_t)it * GRPB);
    kvb[bi] = kn[colbase + it * 16];
  };

  auto compute = [&](int bi) {
    float kv = kvb[bi];
    f32x4 ci = {kv, kv, kv, kv};
    f32x4 acc[4];
    #pragma unroll
    for (int rt = 0; rt < 4; ++rt)
      acc[rt] = __builtin_amdgcn_mfma_scale_f32_16x16x128_f8f6f4(
          af[rt], bbuf[bi], ci, 0, 0,               // cbsz=0 blgp=0: e4m3
          0, 0x7F7F7F7F, 0, 0x7F7F7F7F);            // scales = 1.0 (e8m0 127)
    #pragma unroll
    for (int rt = 0; rt < 4; ++rt)
      #pragma unroll
      for (int j = 0; j < 4; ++j)
        rmin[rt][j] = fminf(rmin[rt][j], acc[rt][j]);
  };

  loadB(0, 0);
  loadB(1, 1);

  // 57 iters: 27 doubles (0..53) + 3-iter tail; loads 2 iters ahead
  int k = 0;
  #pragma unroll 1
  for (int tri = 0; tri < 27; ++tri, k += 2) {
    compute(0); loadB(0, k + 2);
    compute(1); loadB(1, k + 3);
  }
  // k == 54; in flight: (0,54),(1,55)
  compute(0); loadB(0, 56);   // iter 54
  compute(1);                  // iter 55
  compute(0);                  // iter 56

  // min over the 16 key-cols (l15 lanes), then device atomicMin per row
  #pragma unroll
  for (int rt = 0; rt < 4; ++rt)
    #pragma unroll
    for (int j = 0; j < 4; ++j) {
      float m = rmin[rt][j];
      m = fminf(m, __shfl_xor(m, 1, 64));
      m = fminf(m, __shfl_xor(m, 2, 64));
      m = fminf(m, __shfl_xor(m, 4, 64));
      m = fminf(m, __shfl_xor(m, 8, 64));
      if (l15 == 0) {
        unsigned bu = __float_as_uint(m);
        unsigned tu = bu ^ (unsigned)(((int)bu >> 31) | (int)0x80000000);
        atomicMin(&rminb[brow + rt * 16 + l4 * 4 + j], tu);
      }
    }
}

// ------ final: decode + add qn + deterministic sum (one block) ------------
__global__ __launch_bounds__(1024) void final_kernel(
    const unsigned* __restrict__ rminb, const float* __restrict__ qn,
    float* __restrict__ out) {
  int t = threadIdx.x;
  float s = 0.f;
  for (int i = t; i < NP; i += 1024) {
    unsigned u = rminb[i];
    unsigned bu = (u & 0x80000000u) ? (u ^ 0x80000000u) : ~u;
    s += __uint_as_float(bu) + qn[i];
  }
  #pragma unroll
  for (int off = 32; off; off >>= 1) s += __shfl_down(s, off, 64);
  __shared__ float red[16];
  if ((t & 63) == 0) red[t >> 6] = s;
  __syncthreads();
  if (t == 0) {
    float tot = 0.f;
    #pragma unroll
    for (int i2 = 0; i2 < 16; ++i2) tot += red[i2];
    out[0] = tot;
  }
}

extern "C" void kernel_launch(void* const* d_in, const int* in_sizes, int n_in,
                              void* d_out, int out_size, void* d_ws, size_t ws_size,
                              hipStream_t stream) {
  const float* resv = (const float*)d_in[0];
  const float* valv = (const float*)d_in[1];
  char* ws = (char*)d_ws;
  unsigned char* Qb = (unsigned char*)ws;            // 1,400,832 B
  unsigned char* Kb = (unsigned char*)(ws + 1400832);// 1,400,832 B
  float* qn         = (float*)(ws + 2801664);        //    58,368 B
  float* kn         = (float*)(ws + 2860032);        //    58,368 B
  unsigned* rminb   = (unsigned*)(ws + 2918400);     //    58,368 B
  float* out = (float*)d_out;

  prep_kernel<<<7296, 256, 0, stream>>>(resv, valv, Qb, Kb, qn, kn, rminb);
  knn_kernel<<<3648, 64, 0, stream>>>(Qb, Kb, kn, rminb);
  final_kernel<<<1, 1024, 0, stream>>>(rminb, qn, out);
}